// Round 4
// baseline (465.029 us; speedup 1.0000x reference)
//
#include <hip/hip_runtime.h>

#define B_ 8
#define C_ 512
#define T_ 2048
#define E_ 512
#define LN_EPS 1e-5f

typedef __attribute__((ext_vector_type(8))) short bf16x8;
typedef __attribute__((ext_vector_type(4))) float f32x4;

__device__ __forceinline__ unsigned short f2bf(float f) {
  union { float f; unsigned u; } v; v.f = f;
  unsigned u = v.u;
  u += 0x7fff + ((u >> 16) & 1);   // RNE
  return (unsigned short)(u >> 16);
}
__device__ __forceinline__ float bf2f(unsigned short h) {
  union { unsigned u; float f; } v; v.u = ((unsigned)h) << 16;
  return v.f;
}

// async global->LDS, 16B/lane; LDS dest = wave-uniform base + lane*16
__device__ __forceinline__ void gl2lds16(const unsigned short* g, unsigned short* l) {
  __builtin_amdgcn_global_load_lds(
      (const __attribute__((address_space(1))) unsigned int*)g,
      (__attribute__((address_space(3))) unsigned int*)l, 16, 0, 0);
}

// x [B,C,T] fp32 -> residual [B,T,C] bf16
__global__ __launch_bounds__(256) void transpose_x(const float* __restrict__ x,
    unsigned short* __restrict__ rb) {
  __shared__ float tile[32][33];
  int b = blockIdx.z;
  int t0 = blockIdx.x * 32, c0 = blockIdx.y * 32;
  int tx = threadIdx.x, ty = threadIdx.y;  // 32 x 8
  const float* xb = x + (long)b * C_ * T_;
#pragma unroll
  for (int i = 0; i < 4; i++)
    tile[ty + i * 8][tx] = xb[(long)(c0 + ty + i * 8) * T_ + t0 + tx];
  __syncthreads();
  long ob = (long)b * T_ * C_;
#pragma unroll
  for (int i = 0; i < 4; i++)
    rb[ob + (long)(t0 + ty + i * 8) * C_ + c0 + tx] = f2bf(tile[tx][ty + i * 8]);
}

// all four W [C,E] fp32 -> Wt [E,C] bf16 in one launch (z selects)
__global__ __launch_bounds__(256) void transpose_w4(
    const float* __restrict__ Wq, const float* __restrict__ Wk,
    const float* __restrict__ Wv, const float* __restrict__ Wo,
    unsigned short* __restrict__ WqkT, unsigned short* __restrict__ WvT,
    unsigned short* __restrict__ WoT) {
  __shared__ float tile[32][33];
  int z = blockIdx.z;
  const float* W = (z == 0) ? Wq : (z == 1) ? Wk : (z == 2) ? Wv : Wo;
  unsigned short* D = (z == 0) ? WqkT : (z == 1) ? (WqkT + 512 * 512)
                     : (z == 2) ? WvT : WoT;
  int e0 = blockIdx.x * 32, c0 = blockIdx.y * 32;
  int tx = threadIdx.x, ty = threadIdx.y;
#pragma unroll
  for (int i = 0; i < 4; i++)
    tile[ty + i * 8][tx] = W[(long)(c0 + ty + i * 8) * E_ + e0 + tx];
  __syncthreads();
#pragma unroll
  for (int i = 0; i < 4; i++)
    D[(long)(e0 + ty + i * 8) * C_ + c0 + tx] = f2bf(tile[tx][ty + i * 8]);
}

__global__ void concat_bias(const float* __restrict__ bq, const float* __restrict__ bk,
                            float* __restrict__ bqk) {
  int i = blockIdx.x * 256 + threadIdx.x;   // 0..1023
  bqk[i] = (i < 512) ? bq[i] : bk[i - 512];
}

// C[m][n] = sum_k A[m][k]*Bt[n][k], bf16 in/out. BK=64, XOR-swizzled LDS.
// EPI: 0=+bias[n]; 1=+bias[m]; 2=+bias[n]+resid; 4=plain; 5=plain + row softmax stats.
template<int EPI, int BM>
__global__ __launch_bounds__(256) void gemm_bt(
    const unsigned short* __restrict__ Ap, const unsigned short* __restrict__ Btp,
    unsigned short* __restrict__ Cp, const float* __restrict__ bias,
    const unsigned short* __restrict__ resid, float2* __restrict__ statsp,
    int K, int lda, int ldb, int ldc, long sA, long sB, long sC) {
  __shared__ unsigned short As[BM * 64];
  __shared__ unsigned short Bs[128 * 64];
  __shared__ float2 sred[(EPI == 5) ? 128 : 1][2];
  constexpr int WI = BM / 32;
  const int b = blockIdx.z;
  const int tid = threadIdx.x;
  const int lane = tid & 63, wave = tid >> 6;
  const int wr = (wave >> 1) * (BM / 2);
  const int wc = (wave & 1) * 64;
  const int quad = lane >> 4, l16 = lane & 15;
  const long m0 = (long)blockIdx.y * BM, n0 = (long)blockIdx.x * 128;

  const int srow = lane >> 3;
  const int gcol = ((lane & 7) ^ srow) * 8;
  const unsigned short* ga = Ap + (long)b * sA + (m0 + srow) * (long)lda + gcol;
  const unsigned short* gb = Btp + (long)b * sB + (n0 + srow) * (long)ldb + gcol;

  f32x4 acc[WI][4] = {};

  for (int k0 = 0; k0 < K; k0 += 64) {
    __syncthreads();
#pragma unroll
    for (int s = 0; s < WI; s++)
      gl2lds16(ga + (s * 32 + wave * 8) * (long)lda + k0, &As[(s * 32 + wave * 8) * 64]);
#pragma unroll
    for (int s = 0; s < 4; s++)
      gl2lds16(gb + (s * 32 + wave * 8) * (long)ldb + k0, &Bs[(s * 32 + wave * 8) * 64]);
    __syncthreads();
#pragma unroll
    for (int ks = 0; ks < 2; ks++) {
      const int cs = ((ks * 4 + quad) ^ (l16 & 7)) * 8;
      bf16x8 af[WI], bfr[4];
#pragma unroll
      for (int i = 0; i < WI; i++)
        af[i] = *(const bf16x8*)&As[(wr + i * 16 + l16) * 64 + cs];
#pragma unroll
      for (int j = 0; j < 4; j++)
        bfr[j] = *(const bf16x8*)&Bs[(wc + j * 16 + l16) * 64 + cs];
#pragma unroll
      for (int i = 0; i < WI; i++)
#pragma unroll
        for (int j = 0; j < 4; j++)
          acc[i][j] = __builtin_amdgcn_mfma_f32_16x16x32_bf16(af[i], bfr[j], acc[i][j], 0, 0, 0);
    }
  }

  const long cb = (long)b * sC;
#pragma unroll
  for (int i = 0; i < WI; i++) {
#pragma unroll
    for (int rr = 0; rr < 4; rr++) {
      const long m = m0 + wr + i * 16 + quad * 4 + rr;
      if constexpr (EPI == 5) {
        float vv[4];
        float mx = -1e30f;
#pragma unroll
        for (int j = 0; j < 4; j++) {
          const long n = n0 + wc + j * 16 + l16;
          unsigned short ub = f2bf(acc[i][j][rr]);
          Cp[cb + m * (long)ldc + n] = ub;
          vv[j] = bf2f(ub);
          mx = fmaxf(mx, vv[j]);
        }
        float sm = 0.f;
#pragma unroll
        for (int j = 0; j < 4; j++) sm += __expf(vv[j] - mx);
#pragma unroll
        for (int o = 1; o < 16; o <<= 1) {
          float om = __shfl_xor(mx, o, 64);
          float os = __shfl_xor(sm, o, 64);
          float nm = fmaxf(mx, om);
          sm = sm * __expf(mx - nm) + os * __expf(om - nm);
          mx = nm;
        }
        if (l16 == 0) sred[wr + i * 16 + quad * 4 + rr][wave & 1] = make_float2(mx, sm);
      } else {
#pragma unroll
        for (int j = 0; j < 4; j++) {
          const long n = n0 + wc + j * 16 + l16;
          float v = acc[i][j][rr];
          if (EPI == 0) v += bias[n];
          else if (EPI == 1) v += bias[m];
          else if (EPI == 2) v += bias[n] + bf2f(resid[m * (long)ldc + n]);
          Cp[cb + m * (long)ldc + n] = f2bf(v);
        }
      }
    }
  }
  if constexpr (EPI == 5) {
    __syncthreads();
    if (tid < 128) {
      float2 a0 = sred[tid][0], a1 = sred[tid][1];
      float M = fmaxf(a0.x, a1.x);
      float S = a0.y * __expf(a0.x - M) + a1.y * __expf(a1.x - M);
      statsp[((long)b * T_ + m0 + tid) * 16 + blockIdx.x] = make_float2(M, S);
    }
  }
}

// reduce 16 per-block partials -> (M, 1/S) per row
__global__ __launch_bounds__(256) void combine_stats(const float2* __restrict__ sp,
                                                     float2* __restrict__ rs) {
  long row = blockIdx.x * 256L + threadIdx.x;
  const float2* p = sp + row * 16;
  float M = -1e30f;
#pragma unroll
  for (int i = 0; i < 16; i++) M = fmaxf(M, p[i].x);
  float S = 0.f;
#pragma unroll
  for (int i = 0; i < 16; i++) S += p[i].y * __expf(p[i].x - M);
  rs[row] = make_float2(M, 1.f / S);
}

// fused softmax + PV: A = exp(energy - M)*invS (bf16, staged via VGPR),
// writes f32 attn (blockIdx.x==0 only), B = vt via DMA. BM=64, BN=128, BK=64.
__global__ __launch_bounds__(256) void pv_fused(
    const unsigned short* __restrict__ eb, const unsigned short* __restrict__ vt,
    const float2* __restrict__ rowstats, float* __restrict__ attn_f,
    unsigned short* __restrict__ att) {
  __shared__ unsigned short As[64 * 64];
  __shared__ unsigned short Bs[128 * 64];
  const int b = blockIdx.z;
  const int tid = threadIdx.x;
  const int lane = tid & 63, wave = tid >> 6;
  const int wr = (wave >> 1) * 32, wc = (wave & 1) * 64;
  const int quad = lane >> 4, l16 = lane & 15;
  const long m0 = (long)blockIdx.y * 64, n0 = (long)blockIdx.x * 128;
  const bool writer = (blockIdx.x == 0);

  // B (vt) DMA staging
  const int srow = lane >> 3;
  const int gcolB = ((lane & 7) ^ srow) * 8;
  const unsigned short* gb = vt + (long)b * 512 * 2048 + (n0 + srow) * 2048L + gcolB;

  // A (energy) VGPR staging: thread -> row ar, chunks pg0 and pg0+4
  const int ar = tid >> 2;
  const int pg0 = tid & 3;
  const long arow = (long)b * T_ + m0 + ar;
  const unsigned short* ga = eb + arow * (long)T_ + pg0 * 8;
  float* fo = attn_f + arow * (long)T_ + pg0 * 8;
  const float2 st = rowstats[arow];
  const float negM = -st.x, inv = st.y;
  const int pL0 = (pg0 ^ (ar & 7)) * 8;
  const int pL1 = ((pg0 + 4) ^ (ar & 7)) * 8;

  f32x4 acc[2][4] = {};

  for (int k0 = 0; k0 < T_; k0 += 64) {
    __syncthreads();
#pragma unroll
    for (int s = 0; s < 4; s++)
      gl2lds16(gb + (s * 32 + wave * 8) * 2048L + k0, &Bs[(s * 32 + wave * 8) * 64]);
    bf16x8 r0 = *(const bf16x8*)(ga + k0);
    bf16x8 r1 = *(const bf16x8*)(ga + k0 + 32);
    unsigned short p0[8], p1[8];
    float f0[8], f1[8];
#pragma unroll
    for (int j = 0; j < 8; j++) {
      float pa = __expf(bf2f((unsigned short)r0[j]) + negM) * inv;
      f0[j] = pa; p0[j] = f2bf(pa);
      float pb = __expf(bf2f((unsigned short)r1[j]) + negM) * inv;
      f1[j] = pb; p1[j] = f2bf(pb);
    }
    if (writer) {
      *(float4*)(fo + k0)      = *(float4*)&f0[0];
      *(float4*)(fo + k0 + 4)  = *(float4*)&f0[4];
      *(float4*)(fo + k0 + 32) = *(float4*)&f1[0];
      *(float4*)(fo + k0 + 36) = *(float4*)&f1[4];
    }
    *(bf16x8*)&As[ar * 64 + pL0] = *(bf16x8*)p0;
    *(bf16x8*)&As[ar * 64 + pL1] = *(bf16x8*)p1;
    __syncthreads();
#pragma unroll
    for (int ks = 0; ks < 2; ks++) {
      const int cs = ((ks * 4 + quad) ^ (l16 & 7)) * 8;
      bf16x8 af[2], bfr[4];
      af[0] = *(const bf16x8*)&As[(wr + l16) * 64 + cs];
      af[1] = *(const bf16x8*)&As[(wr + 16 + l16) * 64 + cs];
#pragma unroll
      for (int j = 0; j < 4; j++)
        bfr[j] = *(const bf16x8*)&Bs[(wc + j * 16 + l16) * 64 + cs];
#pragma unroll
      for (int i = 0; i < 2; i++)
#pragma unroll
        for (int j = 0; j < 4; j++)
          acc[i][j] = __builtin_amdgcn_mfma_f32_16x16x32_bf16(af[i], bfr[j], acc[i][j], 0, 0, 0);
    }
  }

#pragma unroll
  for (int i = 0; i < 2; i++)
#pragma unroll
    for (int rr = 0; rr < 4; rr++) {
      const long m = m0 + wr + i * 16 + quad * 4 + rr;
#pragma unroll
      for (int j = 0; j < 4; j++) {
        const long n = n0 + wc + j * 16 + l16;
        att[((long)b * T_ + m) * 512 + n] = f2bf(acc[i][j][rr]);
      }
    }
}

// LayerNorm over rows of 512, bf16 input, f32 output
__global__ __launch_bounds__(256) void layernorm_rows(const unsigned short* __restrict__ hb,
    const float* __restrict__ gamma, const float* __restrict__ beta,
    float* __restrict__ out) {
  long row = blockIdx.x;
  const unsigned short* p = hb + row * C_;
  int tid = threadIdx.x;
  unsigned pr = *(const unsigned*)(p + 2 * tid);
  float v0 = bf2f((unsigned short)(pr & 0xffff));
  float v1 = bf2f((unsigned short)(pr >> 16));
  float s = v0 + v1, sq = v0 * v0 + v1 * v1;
#pragma unroll
  for (int o = 32; o > 0; o >>= 1) { s += __shfl_xor(s, o, 64); sq += __shfl_xor(sq, o, 64); }
  __shared__ float rs[4], rq[4];
  if ((tid & 63) == 0) { rs[tid >> 6] = s; rq[tid >> 6] = sq; }
  __syncthreads();
  s = rs[0] + rs[1] + rs[2] + rs[3];
  sq = rq[0] + rq[1] + rq[2] + rq[3];
  float mu = s * (1.f / 512.f);
  float var = sq * (1.f / 512.f) - mu * mu;
  float rstd = rsqrtf(var + LN_EPS);
  out[row * C_ + 2 * tid]     = (v0 - mu) * rstd * gamma[2 * tid] + beta[2 * tid];
  out[row * C_ + 2 * tid + 1] = (v1 - mu) * rstd * gamma[2 * tid + 1] + beta[2 * tid + 1];
}

extern "C" void kernel_launch(void* const* d_in, const int* in_sizes, int n_in,
                              void* d_out, int out_size, void* d_ws, size_t ws_size,
                              hipStream_t stream) {
  const float* x  = (const float*)d_in[0];
  const float* Wq = (const float*)d_in[1];
  const float* bq = (const float*)d_in[2];
  const float* Wk = (const float*)d_in[3];
  const float* bk = (const float*)d_in[4];
  const float* Wv = (const float*)d_in[5];
  const float* bv = (const float*)d_in[6];
  const float* Wo = (const float*)d_in[7];
  const float* bo = (const float*)d_in[8];
  const float* gamma = (const float*)d_in[9];
  const float* beta  = (const float*)d_in[10];
  float* out = (float*)d_out;

  char* ws = (char*)d_ws;
  unsigned short* res_b = (unsigned short*)ws;                          // 16 MB [16384][512]
  unsigned short* qk    = (unsigned short*)(ws + (16ul << 20));         // 32 MB [16384][1024]
  unsigned short* att   = (unsigned short*)(ws + (16ul << 20));         // overlay (q dead)
  unsigned short* hb    = (unsigned short*)(ws + (32ul << 20));         // overlay (k dead)
  unsigned short* vt    = (unsigned short*)(ws + (48ul << 20));         // 16 MB [b][512][2048]
  unsigned short* eb    = (unsigned short*)(ws + (64ul << 20));         // 64 MB [b][2048][2048]
  unsigned short* WqkT  = (unsigned short*)(ws + (128ul << 20));        // 2 MB [1024][512]
  unsigned short* WvT   = (unsigned short*)(ws + (130ul << 20));        // 512 KB
  unsigned short* WoT   = (unsigned short*)(ws + (130ul << 20) + 524288);
  float*          bqk   = (float*)(ws + (131ul << 20));                 // 4 KB
  float2* statsp   = (float2*)(ws + (128ul << 20));   // 2 MB, reuses WqkT (dead post-qk)
  float2* rowstats = (float2*)(ws + (130ul << 20));   // 128 KB, reuses WvT (dead post-vt)

  float* attn_f = out;                        // [B,T,T]
  float* outln  = out + (long)B_ * T_ * T_;   // [B,T,C]

  dim3 tb(32, 8);
  transpose_x<<<dim3(T_ / 32, C_ / 32, B_), tb, 0, stream>>>(x, res_b);
  transpose_w4<<<dim3(16, 16, 4), tb, 0, stream>>>(Wq, Wk, Wv, Wo, WqkT, WvT, WoT);
  concat_bias<<<dim3(4), 256, 0, stream>>>(bq, bk, bqk);

  // qk = res @ [Wq|Wk] + [bq|bk]   [16384 x 1024], K=512
  gemm_bt<0, 128><<<dim3(8, 128, 1), 256, 0, stream>>>(
      res_b, WqkT, qk, bqk, nullptr, nullptr, 512, 512, 512, 1024, 0L, 0L, 0L);
  // vt[b][e][s] = WvT[e,:] . res[b][s,:] + bv[e]
  gemm_bt<1, 64><<<dim3(16, 8, B_), 256, 0, stream>>>(
      WvT, res_b, vt, bv, nullptr, nullptr, 512, 512, 512, 2048,
      0L, (long)T_ * C_, 512L * 2048);
  // energy bf16 + per-block softmax stats partials
  gemm_bt<5, 128><<<dim3(16, 16, B_), 256, 0, stream>>>(
      qk, qk + 512, eb, nullptr, nullptr, statsp, 512, 1024, 1024, 2048,
      (long)T_ * 1024, (long)T_ * 1024, (long)T_ * T_);
  // per-row (M, 1/S)
  combine_stats<<<dim3(64), 256, 0, stream>>>(statsp, rowstats);
  // fused softmax + PV; writes f32 attn to d_out
  pv_fused<<<dim3(4, 32, B_), 256, 0, stream>>>(eb, vt, rowstats, attn_f, att);
  // h = att @ WoT^T + bo + resid (bf16)
  gemm_bt<2, 64><<<dim3(4, 256, 1), 256, 0, stream>>>(
      att, WoT, hb, bo, res_b, nullptr, 512, 512, 512, 512, 0L, 0L, 0L);
  // LayerNorm
  layernorm_rows<<<dim3(B_ * T_), 256, 0, stream>>>(hb, gamma, beta, outln);
}